// Round 5
// baseline (260.789 us; speedup 1.0000x reference)
//
#include <hip/hip_runtime.h>

#define DIMX 512
#define HEADSX 4
#define DHX 128
#define CHX 16
#define NCX 128
#define SX 2048
#define BX 2
#define BHX 8
#define PADF 136   // stage LDS row pad (ushorts): 136*2B = 272B = 17*16B (b128-aligned)

typedef unsigned short ushort_t;
typedef unsigned int uint_t;
typedef short bf16x8 __attribute__((ext_vector_type(8)));
typedef float f32x4 __attribute__((ext_vector_type(4)));

__device__ __forceinline__ float sigmoidf_(float z){ return 1.0f/(1.0f + __expf(-z)); }

__device__ __forceinline__ ushort_t f2bf(float f){
  uint_t u = __float_as_uint(f);
  return (ushort_t)((u + 0x7FFFu + ((u >> 16) & 1u)) >> 16);
}
__device__ __forceinline__ uint_t pk2(float a, float b){
  return (uint_t)f2bf(a) | ((uint_t)f2bf(b) << 16);
}

// ---------------- K-prep2: weight layouts ----------------
// blocks 0..63 : WkvT2[n][k] = f2bf(scale[k]*Wkv[k][n])  (n=0..1023, k=0..511)
// blocks 64..71: per-bh w0T/w1T (transposed), w1n (natural)
// block  72    : wfs{S,M,D}[d*4+h] = scale[d] * W{step,mom,dec}[d][h]
__global__ __launch_bounds__(256) void k_prep2(const float* __restrict__ Wkv,
    const float* __restrict__ w0, const float* __restrict__ w1,
    const float* __restrict__ scale,
    const float* __restrict__ Wstep, const float* __restrict__ Wmom,
    const float* __restrict__ Wdec,
    ushort_t* __restrict__ WkvT2, ushort_t* __restrict__ w0T,
    ushort_t* __restrict__ w1T, ushort_t* __restrict__ w1n,
    float* __restrict__ wfsS, float* __restrict__ wfsM, float* __restrict__ wfsD){
  int blk = blockIdx.x; int tid = threadIdx.x;
  if (blk < 64){
    int n0 = blk*16;
    __shared__ ushort_t tile[16][520];   // [n][k], row = 1040B = 65*16B
    #pragma unroll
    for (int rr=0; rr<2; rr++){
      int k = tid*2 + rr;
      float sc = scale[k];
      #pragma unroll
      for (int f=0; f<4; f++){
        float4 v = *(const float4*)&Wkv[(size_t)k*1024 + n0 + f*4];
        tile[f*4+0][k] = f2bf(sc*v.x);
        tile[f*4+1][k] = f2bf(sc*v.y);
        tile[f*4+2][k] = f2bf(sc*v.z);
        tile[f*4+3][k] = f2bf(sc*v.w);
      }
    }
    __syncthreads();
    int nr = tid >> 4, seg = tid & 15;
    const uint4* s = (const uint4*)&tile[nr][seg*32];
    uint4* d = (uint4*)&WkvT2[(size_t)(n0+nr)*512 + seg*32];
    d[0]=s[0]; d[1]=s[1]; d[2]=s[2]; d[3]=s[3];
  } else if (blk < 72){
    int bh = blk - 64;
    size_t base = (size_t)bh*16384;
    for (int i=tid; i<16384; i+=256){
      int r = i >> 7, c = i & 127;
      w0T[base + i] = f2bf(w0[base + (size_t)c*128 + r]);
      w1T[base + i] = f2bf(w1[base + (size_t)c*128 + r]);
      w1n[base + i] = f2bf(w1[base + i]);
    }
  } else {
    for (int i=tid; i<2048; i+=256){
      float sc = scale[i>>2];
      wfsS[i] = sc * Wstep[i];
      wfsM[i] = sc * Wmom [i];
      wfsD[i] = sc * Wdec [i];
    }
  }
}

// ---------------- K-stats2: RMS + lr + mom/dec + bf16 x-hat ----------------
// 256 blocks = (b, chunk), 256 threads: token c = tid>>4, slice sl = tid&15.
// Lane's float4 columns: sl + 16*jj  (16 lanes of a token read 256B contiguous).
// Writes xhat = bf16(seq*rs) (scale folded into WkvT2 / wfs tables).
__global__ __launch_bounds__(256) void k_stats2(const float* __restrict__ seq,
    const float* __restrict__ wfsS, const float* __restrict__ wfsM,
    const float* __restrict__ wfsD,
    ushort_t* __restrict__ xhat, float* __restrict__ lrbuf,
    float* __restrict__ momw, float* __restrict__ decw){
  int blk = blockIdx.x;
  int b = blk >> 7, nc = blk & 127;
  int tid = threadIdx.x;
  int wv = tid >> 6, lane = tid & 63;
  int c = tid >> 4, sl = tid & 15;
  size_t tok = (size_t)(b*SX + nc*CHX + c);
  const float4* sr = (const float4*)(seq + tok*DIMX);
  float4 q[8];
  #pragma unroll
  for (int jj=0; jj<8; jj++) q[jj] = sr[sl + 16*jj];

  float ss=0.f;
  float lp[4]={0,0,0,0}, pm[4]={0,0,0,0}, pd[4]={0,0,0,0};
  #pragma unroll
  for (int jj=0; jj<8; jj++){
    int d0 = (sl + 16*jj)*4;
    float qx=q[jj].x, qy=q[jj].y, qz=q[jj].z, qw=q[jj].w;
    ss += qx*qx + qy*qy + qz*qz + qw*qw;
    #pragma unroll
    for (int e=0; e<4; e++){
      float qe = (e==0)?qx:(e==1)?qy:(e==2)?qz:qw;
      float4 tS = *(const float4*)&wfsS[(size_t)(d0+e)*4];
      float4 tM = *(const float4*)&wfsM[(size_t)(d0+e)*4];
      float4 tD = *(const float4*)&wfsD[(size_t)(d0+e)*4];
      lp[0]+=qe*tS.x; lp[1]+=qe*tS.y; lp[2]+=qe*tS.z; lp[3]+=qe*tS.w;
      pm[0]+=qe*tM.x; pm[1]+=qe*tM.y; pm[2]+=qe*tM.z; pm[3]+=qe*tM.w;
      pd[0]+=qe*tD.x; pd[1]+=qe*tD.y; pd[2]+=qe*tD.z; pd[3]+=qe*tD.w;
    }
  }
  // butterfly within the token's 16 lanes
  #pragma unroll
  for (int mk=1; mk<16; mk<<=1){
    ss += __shfl_xor(ss, mk, 64);
    #pragma unroll
    for (int hh=0; hh<4; hh++){
      lp[hh]+=__shfl_xor(lp[hh],mk,64);
      pm[hh]+=__shfl_xor(pm[hh],mk,64);
      pd[hh]+=__shfl_xor(pd[hh],mk,64);
    }
  }
  float rs = 1.0f / sqrtf(ss*(1.0f/DIMX) + 1e-6f);

  // x-hat write (bf16, 8B/lane, contiguous per token group)
  #pragma unroll
  for (int jj=0; jj<8; jj++){
    uint2 u;
    u.x = pk2(q[jj].x*rs, q[jj].y*rs);
    u.y = pk2(q[jj].z*rs, q[jj].w*rs);
    *(uint2*)&xhat[tok*DIMX + (size_t)(sl+16*jj)*4] = u;
  }
  // per-token lr (4 heads)
  if (sl == 0){
    #pragma unroll
    for (int hh=0; hh<4; hh++)
      lrbuf[(size_t)(b*HEADSX+hh)*SX + nc*CHX + c] = 0.01f * sigmoidf_(rs*lp[hh]);
  }
  // chunk-level mom/dec: sum rs*pm over the 16 tokens
  float pmr[4], pdr[4];
  #pragma unroll
  for (int hh=0; hh<4; hh++){ pmr[hh]=rs*pm[hh]; pdr[hh]=rs*pd[hh]; }
  #pragma unroll
  for (int mk=16; mk<64; mk<<=1){
    #pragma unroll
    for (int hh=0; hh<4; hh++){
      pmr[hh]+=__shfl_xor(pmr[hh],mk,64);
      pdr[hh]+=__shfl_xor(pdr[hh],mk,64);
    }
  }
  __shared__ float redm[4][4], redd[4][4];
  if (lane == 0){
    #pragma unroll
    for (int hh=0; hh<4; hh++){ redm[wv][hh]=pmr[hh]; redd[wv][hh]=pdr[hh]; }
  }
  __syncthreads();
  if (tid < 8){
    int hh = tid & 3; bool isd = tid >= 4;
    float v = isd ? (redd[0][hh]+redd[1][hh]+redd[2][hh]+redd[3][hh])
                  : (redm[0][hh]+redm[1][hh]+redm[2][hh]+redm[3][hh]);
    float sg = sigmoidf_(v*(1.0f/CHX));
    int bt = (b*HEADSX+hh)*NCX + nc;
    if (isd) decw[bt] = 1.0f - sg; else momw[bt] = sg;
  }
}

// ---------------- K-kv2: KV projection as a tall-skinny GEMM ----------------
// 512 blocks x 512 threads (8 waves). blk = nb*64 + mb:
//   mb: b = mb>>5, token rows (mb&31)*64 .. +63  (4 chunks)
//   nb: <4 -> k of head nb ; >=4 -> v of head nb-4 (128 cols each)
// Wave w owns cols w*16..w*16+15. Each B fragment feeds 4 MFMAs (M=64):
// 4x B-load amortization vs the old per-chunk stream. Zero LDS, zero barriers.
__global__ __launch_bounds__(512) void k_kv2(const ushort_t* __restrict__ xhat,
    const ushort_t* __restrict__ WkvT2,
    ushort_t* __restrict__ kbuf, float* __restrict__ vbuf){
  int blk = blockIdx.x;
  int nb = blk >> 6, mb = blk & 63;
  int b = mb >> 5;
  int mrow0 = (mb & 31) * 64;
  int isv = nb >> 2, h = nb & 3;
  int bh = b*HEADSX + h;
  int tid = threadIdx.x;
  int wv = tid >> 6, lane = tid & 63;
  int quad = lane >> 4, nl = lane & 15;
  const f32x4 zero = {0.f,0.f,0.f,0.f};

  const ushort_t* xb = xhat + ((size_t)b*SX + mrow0)*DIMX + nl*DIMX + quad*8;
  const ushort_t* brow = WkvT2 + ((size_t)nb*128 + wv*16 + nl)*DIMX + quad*8;

  f32x4 acc[4] = {zero,zero,zero,zero};
  #pragma unroll
  for (int kt=0; kt<16; kt++){
    bf16x8 Bf = *(const bf16x8*)(brow + kt*32);
    #pragma unroll
    for (int mf=0; mf<4; mf++){
      bf16x8 Af = *(const bf16x8*)(xb + (size_t)(mf*16)*DIMX + kt*32);
      acc[mf] = __builtin_amdgcn_mfma_f32_16x16x32_bf16(Af, Bf, acc[mf], 0,0,0);
    }
  }
  int p = wv*16 + nl;
  #pragma unroll
  for (int mf=0; mf<4; mf++){
    int t = (mb & 31)*4 + mf;
    size_t bt = (size_t)bh*NCX + t;
    if (isv){
      #pragma unroll
      for (int r=0;r<4;r++)
        vbuf[(bt*16 + quad*4 + r)*128 + p] = acc[mf][r];
    } else {
      #pragma unroll
      for (int r=0;r<4;r++)
        kbuf[(bt*16 + quad*4 + r)*128 + p] = f2bf(acc[mf][r]);
    }
  }
}

// ---------------- K-mlp2: per-chunk gradient factors (4 chained gemms) ----------------
// 1024 blocks x 128 threads (2 waves); block = chunk (bh = blk&7 -> XCD L2 pin).
// Wave w owns n-tiles w*4..w*4+3 in every gemm (so silu' stays in registers).
// A-fragments: gemm1 from kbuf (global, L1-hot), gemm2/3 from LDS stages.
__global__ __launch_bounds__(128) void k_mlp2(const ushort_t* __restrict__ kbuf,
    const float* __restrict__ vbuf, const float* __restrict__ lrbuf,
    const ushort_t* __restrict__ w0T, const ushort_t* __restrict__ w1T,
    const ushort_t* __restrict__ w1n,
    ushort_t* __restrict__ fac0, ushort_t* __restrict__ fac1){
  int blk = blockIdx.x;
  int bh = blk & 7, t = blk >> 3;
  size_t bt = (size_t)bh*NCX + t;
  int tid = threadIdx.x;
  int wv = tid >> 6, lane = tid & 63;
  int quad = lane >> 4, nl = lane & 15;
  const f32x4 zero = {0.f,0.f,0.f,0.f};
  __shared__ __align__(16) ushort_t as_[16*PADF];
  __shared__ __align__(16) ushort_t dp_[16*PADF];
  __shared__ __align__(16) ushort_t dh_[16*PADF];

  const ushort_t* kb = kbuf + bt*16*128;

  // ---- gemm1: h = k @ w0
  const ushort_t* w0b = w0T + (size_t)bh*16384;
  f32x4 hacc[4] = {zero,zero,zero,zero};
  #pragma unroll
  for (int kt=0; kt<4; kt++){
    bf16x8 Af = *(const bf16x8*)(kb + (size_t)nl*128 + kt*32 + quad*8);
    #pragma unroll
    for (int j=0; j<4; j++){
      int n = (wv*4+j)*16 + nl;
      bf16x8 Bf = *(const bf16x8*)(w0b + (size_t)n*128 + kt*32 + quad*8);
      hacc[j] = __builtin_amdgcn_mfma_f32_16x16x32_bf16(Af, Bf, hacc[j], 0,0,0);
    }
  }
  float sp[4][4];
  #pragma unroll
  for (int j=0; j<4; j++){
    #pragma unroll
    for (int r=0; r<4; r++){
      float hh = hacc[j][r];
      float sg = sigmoidf_(hh);
      sp[j][r] = sg*(1.0f + hh*(1.0f-sg));
      as_[(quad*4+r)*PADF + (wv*4+j)*16 + nl] = f2bf(hh*sg);
    }
  }
  __syncthreads();

  // ---- gemm2: pred = a @ w1 ; dpred = 2/DH * lr * (pred - v)
  const ushort_t* w1tb = w1T + (size_t)bh*16384;
  f32x4 pacc[4] = {zero,zero,zero,zero};
  #pragma unroll
  for (int kt=0; kt<4; kt++){
    bf16x8 Af = *(const bf16x8*)&as_[nl*PADF + kt*32 + quad*8];
    #pragma unroll
    for (int j=0; j<4; j++){
      int n = (wv*4+j)*16 + nl;
      bf16x8 Bf = *(const bf16x8*)(w1tb + (size_t)n*128 + kt*32 + quad*8);
      pacc[j] = __builtin_amdgcn_mfma_f32_16x16x32_bf16(Af, Bf, pacc[j], 0,0,0);
    }
  }
  float lrv[4];
  #pragma unroll
  for (int r=0; r<4; r++) lrv[r] = lrbuf[(size_t)bh*SX + t*CHX + quad*4 + r];
  #pragma unroll
  for (int j=0; j<4; j++){
    #pragma unroll
    for (int r=0; r<4; r++){
      int c = quad*4 + r;
      float vv = vbuf[(bt*16 + c)*128 + (wv*4+j)*16 + nl];
      float dp = (2.0f/DHX)*lrv[r]*(pacc[j][r] - vv);
      dp_[c*PADF + (wv*4+j)*16 + nl] = f2bf(dp);
    }
  }
  __syncthreads();

  // ---- gemm3: da = dpred @ w1^T ; dh = da * silu'(h)
  const ushort_t* w1nb = w1n + (size_t)bh*16384;
  f32x4 dacc[4] = {zero,zero,zero,zero};
  #pragma unroll
  for (int kt=0; kt<4; kt++){
    bf16x8 Af = *(const bf16x8*)&dp_[nl*PADF + kt*32 + quad*8];
    #pragma unroll
    for (int j=0; j<4; j++){
      int n = (wv*4+j)*16 + nl;
      bf16x8 Bf = *(const bf16x8*)(w1nb + (size_t)n*128 + kt*32 + quad*8);
      dacc[j] = __builtin_amdgcn_mfma_f32_16x16x32_bf16(Af, Bf, dacc[j], 0,0,0);
    }
  }
  #pragma unroll
  for (int j=0; j<4; j++){
    #pragma unroll
    for (int r=0; r<4; r++)
      dh_[(quad*4+r)*PADF + (wv*4+j)*16 + nl] = f2bf(dacc[j][r]*sp[j][r]);
  }
  __syncthreads();

  // ---- pack rows: fac0[p] = {k c0..15 | a c0..15}, fac1[p] = {dh | dp}
  {
    int p = tid;   // 0..127
    ushort_t rowv[32];
    #pragma unroll
    for (int c=0; c<16; c++){ rowv[c] = kb[(size_t)c*128 + p]; rowv[16+c] = as_[c*PADF + p]; }
    {
      uint4* dq = (uint4*)(fac0 + (bt*128 + p)*32);
      const uint4* rv = (const uint4*)rowv;
      dq[0]=rv[0]; dq[1]=rv[1]; dq[2]=rv[2]; dq[3]=rv[3];
    }
    #pragma unroll
    for (int c=0; c<16; c++){ rowv[c] = dh_[c*PADF + p]; rowv[16+c] = dp_[c*PADF + p]; }
    {
      uint4* dq = (uint4*)(fac1 + (bt*128 + p)*32);
      const uint4* rv = (const uint4*)rowv;
      dq[0]=rv[0]; dq[1]=rv[1]; dq[2]=rv[2]; dq[3]=rv[3];
    }
  }
}

// ---------------- K-scan3: barrier-free, LDS-free MFMA scan (unchanged) ----------------
__global__ __launch_bounds__(64) void k_scan3(const ushort_t* __restrict__ fac0,
    const ushort_t* __restrict__ fac1,
    const float* __restrict__ momw, const float* __restrict__ decw,
    float* __restrict__ out){
  int blk = blockIdx.x;
  int bh  = blk & 7;
  int jb  = (blk >> 3) & 7;
  int ig  = (blk >> 6) & 7;
  int mat = blk >> 9;
  int lane = threadIdx.x;
  int quad = lane >> 4, rrow = lane & 15;
  const f32x4 zero = {0.f,0.f,0.f,0.f};
  const bf16x8 fz = {0,0,0,0,0,0,0,0};

  size_t rowbase = (size_t)bh*NCX*128;
  const ushort_t* pa = fac0 + (rowbase + (size_t)(ig*16 + rrow))*32 + mat*16 + quad*8;
  const ushort_t* pb = fac1 + (rowbase + (size_t)(jb*16 + rrow))*32 + mat*16 + quad*8;
  bool act = (quad < 2);

  bf16x8 fa0=fz, fb0=fz, fa1=fz, fb1=fz;
  if (act){
    fa0 = *(const bf16x8*)(pa);
    fb0 = *(const bf16x8*)(pb);
    fa1 = *(const bf16x8*)(pa + 4096);
    fb1 = *(const bf16x8*)(pb + 4096);
  }

  f32x4 m_ = zero, u_ = zero;
  size_t obase = ((size_t)(mat*BHX + bh)*NCX)*((size_t)DHX*DHX)
               + (size_t)(ig*16 + quad*4)*DHX + (size_t)(jb*16 + rrow);
  const float* mop = momw + bh*NCX;
  const float* dep = decw + bh*NCX;

  for (int t=0; t<NCX; t+=2){
    bf16x8 na0=fz, nb0=fz, na1=fz, nb1=fz;
    if (act && (t+2 < NCX)){
      na0 = *(const bf16x8*)(pa + (size_t)(t+2)*4096);
      nb0 = *(const bf16x8*)(pb + (size_t)(t+2)*4096);
      na1 = *(const bf16x8*)(pa + (size_t)(t+3)*4096);
      nb1 = *(const bf16x8*)(pb + (size_t)(t+3)*4096);
    }
    float mo = mop[t], de = dep[t];
    f32x4 g = __builtin_amdgcn_mfma_f32_16x16x32_bf16(fa0, fb0, zero, 0,0,0);
    float* ob = out + obase + (size_t)t*(DHX*DHX);
    #pragma unroll
    for (int r=0;r<4;r++){
      m_[r] = mo*m_[r] - g[r];
      u_[r] = de*u_[r] + m_[r];
      ob[(size_t)r*DHX] = u_[r];
    }
    mo = mop[t+1]; de = dep[t+1];
    g = __builtin_amdgcn_mfma_f32_16x16x32_bf16(fa1, fb1, zero, 0,0,0);
    ob += (size_t)DHX*DHX;
    #pragma unroll
    for (int r=0;r<4;r++){
      m_[r] = mo*m_[r] - g[r];
      u_[r] = de*u_[r] + m_[r];
      ob[(size_t)r*DHX] = u_[r];
    }
    fa0=na0; fb0=nb0; fa1=na1; fb1=nb1;
  }
}

extern "C" void kernel_launch(void* const* d_in, const int* in_sizes, int n_in,
                              void* d_out, int out_size, void* d_ws, size_t ws_size,
                              hipStream_t stream) {
  (void)in_sizes; (void)n_in; (void)out_size; (void)ws_size;
  const float* seq   = (const float*)d_in[0];
  const float* scale = (const float*)d_in[1];
  const float* Wkv   = (const float*)d_in[2];
  const float* Wstep = (const float*)d_in[3];
  const float* Wmom  = (const float*)d_in[4];
  const float* Wdec  = (const float*)d_in[5];
  const float* w0    = (const float*)d_in[6];
  const float* w1    = (const float*)d_in[7];
  float* out = (float*)d_out;
  float* ws  = (float*)d_ws;

  // workspace layout (float units)
  ushort_t* fac0  = (ushort_t*)(ws);             // 4,194,304 ushorts
  ushort_t* fac1  = (ushort_t*)(ws + 2097152);   // 4,194,304 ushorts
  ushort_t* WkvT2 = (ushort_t*)(ws + 4194304);   // 524,288 ushorts
  ushort_t* w0T   = (ushort_t*)(ws + 4456448);   // 131,072 ushorts
  ushort_t* w1T   = (ushort_t*)(ws + 4521984);   // 131,072 ushorts
  ushort_t* w1n   = (ushort_t*)(ws + 4587520);   // 131,072 ushorts
  ushort_t* xhat  = (ushort_t*)(ws + 4653056);   // 2,097,152 ushorts
  ushort_t* kbuf  = (ushort_t*)(ws + 5701632);   // 2,097,152 ushorts
  float*    vbuf  = ws + 6750208;                // 2,097,152 floats
  float*    lrbuf = ws + 8847360;                // 16,384
  float*    momw  = ws + 8863744;                // 1,024
  float*    decw  = ws + 8864768;                // 1,024
  float*    wfsS  = ws + 8865792;                // 2,048
  float*    wfsM  = ws + 8867840;                // 2,048
  float*    wfsD  = ws + 8869888;                // 2,048

  k_prep2<<<dim3(73), dim3(256), 0, stream>>>(Wkv, w0, w1, scale, Wstep, Wmom, Wdec,
      WkvT2, w0T, w1T, w1n, wfsS, wfsM, wfsD);
  k_stats2<<<dim3(BX*NCX), dim3(256), 0, stream>>>(seq, wfsS, wfsM, wfsD,
      xhat, lrbuf, momw, decw);
  k_kv2<<<dim3(512), dim3(512), 0, stream>>>(xhat, WkvT2, kbuf, vbuf);
  k_mlp2<<<dim3(BHX*NCX), dim3(128), 0, stream>>>(kbuf, vbuf, lrbuf,
      w0T, w1T, w1n, fac0, fac1);
  k_scan3<<<dim3(1024), dim3(64), 0, stream>>>(fac0, fac1, momw, decw, out);
}

// Round 6
// 236.013 us; speedup vs baseline: 1.1050x; 1.1050x over previous
//
#include <hip/hip_runtime.h>

#define DIMX 512
#define HEADSX 4
#define DHX 128
#define CHX 16
#define NCX 128
#define SX 2048
#define BX 2
#define BHX 8
#define PADX 520   // xs LDS row pad (ushorts)
#define PADF 136   // stage LDS row pad (ushorts)

typedef unsigned short ushort_t;
typedef unsigned int uint_t;
typedef short bf16x8 __attribute__((ext_vector_type(8)));
typedef float f32x4 __attribute__((ext_vector_type(4)));

__device__ __forceinline__ float sigmoidf_(float z){ return 1.0f/(1.0f + __expf(-z)); }

// fp32 -> bf16 round-to-nearest-even
__device__ __forceinline__ ushort_t f2bf(float f){
  uint_t u = __float_as_uint(f);
  return (ushort_t)((u + 0x7FFFu + ((u >> 16) & 1u)) >> 16);
}
__device__ __forceinline__ uint_t pk2(float a, float b){
  return (uint_t)f2bf(a) | ((uint_t)f2bf(b) << 16);
}

// ---------------- K-prep: bf16 weight layouts + premultiplied stat tables ----------------
// blocks 0..63 : WkvT[h][kt][col][kk] (raw Wkv, bf16) via LDS transpose
// blocks 64..71: per-bh w0T/w1T (transposed), w1n (natural)
// block  72    : wfs{S,M,D}[h*512+d] = scale[d]*W{step,mom,dec}[d][h]
__global__ __launch_bounds__(256) void k_prep(const float* __restrict__ Wkv,
    const float* __restrict__ w0, const float* __restrict__ w1,
    const float* __restrict__ scale,
    const float* __restrict__ Wstep, const float* __restrict__ Wmom,
    const float* __restrict__ Wdec,
    ushort_t* __restrict__ WkvT, ushort_t* __restrict__ w0T,
    ushort_t* __restrict__ w1T, ushort_t* __restrict__ w1n,
    float* __restrict__ wfsS, float* __restrict__ wfsM, float* __restrict__ wfsD){
  int blk = blockIdx.x; int tid = threadIdx.x;
  if (blk < 64){
    int h = blk >> 4, kt = blk & 15;
    __shared__ ushort_t tile[256][33];   // [col][kk], +1 pad
    for (int i=tid; i<8192; i+=256){
      int kk = i >> 8, col = i & 255;    // coalesced read
      int wcol = (col < 128) ? (h*128 + col) : (384 + h*128 + col);
      float v = Wkv[(size_t)(kt*32+kk)*1024 + wcol];
      tile[col][kk] = f2bf(v);
    }
    __syncthreads();
    for (int i=tid; i<8192; i+=256){
      int col = i >> 5, kk = i & 31;     // coalesced write
      WkvT[(((size_t)h*16 + kt)*256 + col)*32 + kk] = tile[col][kk];
    }
  } else if (blk < 72){
    int bh = blk - 64;
    size_t base = (size_t)bh*16384;
    for (int i=tid; i<16384; i+=256){
      int r = i >> 7, c = i & 127;
      w0T[base + i] = f2bf(w0[base + (size_t)c*128 + r]);
      w1T[base + i] = f2bf(w1[base + (size_t)c*128 + r]);
      w1n[base + i] = f2bf(w1[base + i]);
    }
  } else {
    for (int i=tid; i<2048; i+=256){
      int d = i & 511, h = i >> 9;
      float sc = scale[d];
      wfsS[i] = sc * Wstep[d*4 + h];
      wfsM[i] = sc * Wmom [d*4 + h];
      wfsD[i] = sc * Wdec [d*4 + h];
    }
  }
}

// ---------------- K-fused5: 4-chunk blocks, 16 waves, L1-shared B panels ----------------
// 256 blocks x 1024 threads; block = (bh = blk&7, 4 chunks t4*4..+3). Wave (mi,ni):
// chunk mi, n-slice ni. One block/CU (119KB LDS) = 16 waves/CU with a SHARED head
// B-panel: the 4 same-ni waves read identical B streams -> L1 hits, ~4x less L2
// traffic than fused2's mixed-bh co-residency. Phase0 is stats2-style (16 shuffles
// per group vs fused2's 192). 5 barriers.
__global__ __launch_bounds__(1024, 4) void k_fused5(const float* __restrict__ seq,
    const float* __restrict__ scale,
    const float* __restrict__ wfsS, const float* __restrict__ wfsM,
    const float* __restrict__ wfsD,
    const ushort_t* __restrict__ WkvT, const ushort_t* __restrict__ w0T,
    const ushort_t* __restrict__ w1T, const ushort_t* __restrict__ w1n,
    ushort_t* __restrict__ fac0, ushort_t* __restrict__ fac1,
    float* __restrict__ momw, float* __restrict__ decw){
  int blk = blockIdx.x;
  int bh = blk & 7, t4 = blk >> 3;
  int b = bh >> 2, h = bh & 3;
  int tid = threadIdx.x;
  int wv = tid >> 6;
  int mi = wv >> 2, ni = wv & 3;
  int lane = tid & 63;
  int quad = lane >> 4, nl = lane & 15;
  int tid_g = ni*64 + lane;          // 0..255 within the chunk group
  int t = t4*4 + mi;
  int bt = bh*NCX + t;
  const f32x4 zero = {0.f,0.f,0.f,0.f};

  __shared__ __align__(16) ushort_t xs[4][16*PADX];    // 66.6 KB
  __shared__ __align__(16) ushort_t ks[4][16*PADF];    // 17.4 KB (later reused for dh)
  __shared__ __align__(16) ushort_t as_[4][16*PADF];   // 17.4 KB
  __shared__ __align__(16) ushort_t dp_[4][16*PADF];   // 17.4 KB
  __shared__ float lr_s[4][16];
  __shared__ float red_m[4][4], red_d[4][4];

  // ---- phase 0: stats + normalized bf16 x into LDS (per chunk group)
  {
    int c = tid_g >> 4, sl = tid_g & 15;
    const float4* sr = (const float4*)(seq + ((size_t)(b*SX + t*CHX) + c)*DIMX);
    const float4* scl = (const float4*)scale;
    const float4* wS = (const float4*)(wfsS + h*512);
    const float4* wM = (const float4*)(wfsM + h*512);
    const float4* wD = (const float4*)(wfsD + h*512);
    float4 q[8];
    #pragma unroll
    for (int jj=0; jj<8; jj++) q[jj] = sr[sl + 16*jj];
    float ss=0.f, lp=0.f, pm=0.f, pd=0.f;
    #pragma unroll
    for (int jj=0; jj<8; jj++){
      float4 a = q[jj];
      float4 s4 = wS[sl+16*jj], m4 = wM[sl+16*jj], d4 = wD[sl+16*jj];
      ss += a.x*a.x + a.y*a.y + a.z*a.z + a.w*a.w;
      lp += a.x*s4.x + a.y*s4.y + a.z*s4.z + a.w*s4.w;
      pm += a.x*m4.x + a.y*m4.y + a.z*m4.z + a.w*m4.w;
      pd += a.x*d4.x + a.y*d4.y + a.z*d4.z + a.w*d4.w;
    }
    #pragma unroll
    for (int mk=1; mk<16; mk<<=1){
      ss += __shfl_xor(ss,mk,64); lp += __shfl_xor(lp,mk,64);
      pm += __shfl_xor(pm,mk,64); pd += __shfl_xor(pd,mk,64);
    }
    float rs = 1.0f / sqrtf(ss*(1.0f/DIMX) + 1e-6f);
    if (sl==0) lr_s[mi][c] = 0.01f * sigmoidf_(rs*lp);
    float pmr = rs*pm, pdr = rs*pd;
    #pragma unroll
    for (int mk=16; mk<64; mk<<=1){ pmr += __shfl_xor(pmr,mk,64); pdr += __shfl_xor(pdr,mk,64); }
    if (lane==0){ red_m[mi][ni]=pmr; red_d[mi][ni]=pdr; }
    #pragma unroll
    for (int jj=0; jj<8; jj++){
      float4 s4 = scl[sl+16*jj];
      uint2 u;
      u.x = pk2(q[jj].x*rs*s4.x, q[jj].y*rs*s4.y);
      u.y = pk2(q[jj].z*rs*s4.z, q[jj].w*rs*s4.w);
      *(uint2*)&xs[mi][c*PADX + (sl+16*jj)*4] = u;
    }
  }
  __syncthreads();   // (1) xs, lr_s, red ready
  if (tid_g==0){
    momw[bt] = sigmoidf_((red_m[mi][0]+red_m[mi][1]+red_m[mi][2]+red_m[mi][3])*(1.0f/CHX));
    decw[bt] = 1.0f - sigmoidf_((red_d[mi][0]+red_d[mi][1]+red_d[mi][2]+red_d[mi][3])*(1.0f/CHX));
  }

  // ---- KV gemm: chunk mi (M=16) x N=64 per wave, K=512
  f32x4 kacc[2] = {zero,zero};
  f32x4 vacc[2] = {zero,zero};
  const ushort_t* wkvh = WkvT + (size_t)h*16*256*32;
  for (int kt=0; kt<16; kt++){
    bf16x8 Af = *(const bf16x8*)&xs[mi][nl*PADX + kt*32 + quad*8];
    #pragma unroll
    for (int s=0; s<2; s++){
      int ktile = 2*ni + s;
      bf16x8 Bk = *(const bf16x8*)&wkvh[((size_t)kt*256 + (ktile*16+nl))*32 + quad*8];
      kacc[s] = __builtin_amdgcn_mfma_f32_16x16x32_bf16(Af, Bk, kacc[s], 0,0,0);
      int vtile = 8 + 2*ni + s;
      bf16x8 Bv = *(const bf16x8*)&wkvh[((size_t)kt*256 + (vtile*16+nl))*32 + quad*8];
      vacc[s] = __builtin_amdgcn_mfma_f32_16x16x32_bf16(Af, Bv, vacc[s], 0,0,0);
    }
  }
  #pragma unroll
  for (int s=0;s<2;s++){
    #pragma unroll
    for (int r=0;r<4;r++)
      ks[mi][(quad*4+r)*PADF + 32*ni + 16*s + nl] = f2bf(kacc[s][r]);
  }
  __syncthreads();   // (2) ks ready

  // ---- gemm1: h = k @ w0
  const ushort_t* w0b = w0T + (size_t)bh*16384;
  f32x4 hacc[2] = {zero,zero};
  #pragma unroll
  for (int kt=0; kt<4; kt++){
    bf16x8 Af = *(const bf16x8*)&ks[mi][nl*PADF + kt*32 + quad*8];
    #pragma unroll
    for (int s=0; s<2; s++){
      int n0 = (2*ni+s)*16;
      bf16x8 Bf = *(const bf16x8*)&w0b[(size_t)(n0+nl)*128 + kt*32 + quad*8];
      hacc[s] = __builtin_amdgcn_mfma_f32_16x16x32_bf16(Af, Bf, hacc[s], 0,0,0);
    }
  }
  float sp[2][4];
  #pragma unroll
  for (int s=0;s<2;s++){
    #pragma unroll
    for (int r=0;r<4;r++){
      float hh = hacc[s][r];
      float sg = sigmoidf_(hh);
      sp[s][r] = sg*(1.0f + hh*(1.0f-sg));
      as_[mi][(quad*4+r)*PADF + 32*ni + 16*s + nl] = f2bf(hh*sg);
    }
  }
  __syncthreads();   // (3) as ready

  // ---- gemm2: pred = a @ w1 ; dpred = 2/DH * lr * (pred - v)   (+ pack fac0)
  const ushort_t* w1tb = w1T + (size_t)bh*16384;
  f32x4 pacc[2] = {zero,zero};
  #pragma unroll
  for (int kt=0; kt<4; kt++){
    bf16x8 Af = *(const bf16x8*)&as_[mi][nl*PADF + kt*32 + quad*8];
    #pragma unroll
    for (int s=0; s<2; s++){
      int n0 = (2*ni+s)*16;
      bf16x8 Bf = *(const bf16x8*)&w1tb[(size_t)(n0+nl)*128 + kt*32 + quad*8];
      pacc[s] = __builtin_amdgcn_mfma_f32_16x16x32_bf16(Af, Bf, pacc[s], 0,0,0);
    }
  }
  float lrv[4];
  #pragma unroll
  for (int r=0;r<4;r++) lrv[r] = lr_s[mi][quad*4 + r];
  #pragma unroll
  for (int s=0;s<2;s++){
    #pragma unroll
    for (int r=0;r<4;r++){
      float dp = (2.0f/DHX)*lrv[r]*(pacc[s][r] - vacc[s][r]);
      dp_[mi][(quad*4+r)*PADF + 32*ni + 16*s + nl] = f2bf(dp);
    }
  }
  // pack fac0 rows (reads ks + as_, both stable this phase)
  if (tid_g < 128){
    int p = tid_g;
    ushort_t rowv[32];
    #pragma unroll
    for (int c=0;c<16;c++){ rowv[c] = ks[mi][c*PADF + p]; rowv[16+c] = as_[mi][c*PADF + p]; }
    uint4* dq = (uint4*)(fac0 + ((size_t)bt*128 + p)*32);
    const uint4* rv = (const uint4*)rowv;
    dq[0]=rv[0]; dq[1]=rv[1]; dq[2]=rv[2]; dq[3]=rv[3];
  }
  __syncthreads();   // (4) dp ready; fac0 pack reads done (ks now reusable)

  // ---- gemm3: da = dpred @ w1^T ; dh = da * silu'(h)  -> into ks buffer
  const ushort_t* w1nb = w1n + (size_t)bh*16384;
  f32x4 dacc[2] = {zero,zero};
  #pragma unroll
  for (int kt=0; kt<4; kt++){
    bf16x8 Af = *(const bf16x8*)&dp_[mi][nl*PADF + kt*32 + quad*8];
    #pragma unroll
    for (int s=0; s<2; s++){
      int n0 = (2*ni+s)*16;
      bf16x8 Bf = *(const bf16x8*)&w1nb[(size_t)(n0+nl)*128 + kt*32 + quad*8];
      dacc[s] = __builtin_amdgcn_mfma_f32_16x16x32_bf16(Af, Bf, dacc[s], 0,0,0);
    }
  }
  #pragma unroll
  for (int s=0;s<2;s++){
    #pragma unroll
    for (int r=0;r<4;r++)
      ks[mi][(quad*4+r)*PADF + 32*ni + 16*s + nl] = f2bf(dacc[s][r]*sp[s][r]);
  }
  __syncthreads();   // (5) dh ready

  // ---- pack fac1 rows: {dh | dp}
  if (tid_g < 128){
    int p = tid_g;
    ushort_t rowv[32];
    #pragma unroll
    for (int c=0;c<16;c++){ rowv[c] = ks[mi][c*PADF + p]; rowv[16+c] = dp_[mi][c*PADF + p]; }
    uint4* dq = (uint4*)(fac1 + ((size_t)bt*128 + p)*32);
    const uint4* rv = (const uint4*)rowv;
    dq[0]=rv[0]; dq[1]=rv[1]; dq[2]=rv[2]; dq[3]=rv[3];
  }
}

// ---------------- K-scan3: barrier-free, LDS-free MFMA scan (unchanged; at write roofline) ----------------
__global__ __launch_bounds__(64) void k_scan3(const ushort_t* __restrict__ fac0,
    const ushort_t* __restrict__ fac1,
    const float* __restrict__ momw, const float* __restrict__ decw,
    float* __restrict__ out){
  int blk = blockIdx.x;
  int bh  = blk & 7;
  int jb  = (blk >> 3) & 7;
  int ig  = (blk >> 6) & 7;
  int mat = blk >> 9;
  int lane = threadIdx.x;
  int quad = lane >> 4, rrow = lane & 15;
  const f32x4 zero = {0.f,0.f,0.f,0.f};
  const bf16x8 fz = {0,0,0,0,0,0,0,0};

  size_t rowbase = (size_t)bh*NCX*128;
  const ushort_t* pa = fac0 + (rowbase + (size_t)(ig*16 + rrow))*32 + mat*16 + quad*8;
  const ushort_t* pb = fac1 + (rowbase + (size_t)(jb*16 + rrow))*32 + mat*16 + quad*8;
  bool act = (quad < 2);

  bf16x8 fa0=fz, fb0=fz, fa1=fz, fb1=fz;
  if (act){
    fa0 = *(const bf16x8*)(pa);
    fb0 = *(const bf16x8*)(pb);
    fa1 = *(const bf16x8*)(pa + 4096);
    fb1 = *(const bf16x8*)(pb + 4096);
  }

  f32x4 m_ = zero, u_ = zero;
  size_t obase = ((size_t)(mat*BHX + bh)*NCX)*((size_t)DHX*DHX)
               + (size_t)(ig*16 + quad*4)*DHX + (size_t)(jb*16 + rrow);
  const float* mop = momw + bh*NCX;
  const float* dep = decw + bh*NCX;

  for (int t=0; t<NCX; t+=2){
    bf16x8 na0=fz, nb0=fz, na1=fz, nb1=fz;
    if (act && (t+2 < NCX)){
      na0 = *(const bf16x8*)(pa + (size_t)(t+2)*4096);
      nb0 = *(const bf16x8*)(pb + (size_t)(t+2)*4096);
      na1 = *(const bf16x8*)(pa + (size_t)(t+3)*4096);
      nb1 = *(const bf16x8*)(pb + (size_t)(t+3)*4096);
    }
    float mo = mop[t], de = dep[t];
    f32x4 g = __builtin_amdgcn_mfma_f32_16x16x32_bf16(fa0, fb0, zero, 0,0,0);
    float* ob = out + obase + (size_t)t*(DHX*DHX);
    #pragma unroll
    for (int r=0;r<4;r++){
      m_[r] = mo*m_[r] - g[r];
      u_[r] = de*u_[r] + m_[r];
      ob[(size_t)r*DHX] = u_[r];
    }
    mo = mop[t+1]; de = dep[t+1];
    g = __builtin_amdgcn_mfma_f32_16x16x32_bf16(fa1, fb1, zero, 0,0,0);
    ob += (size_t)DHX*DHX;
    #pragma unroll
    for (int r=0;r<4;r++){
      m_[r] = mo*m_[r] - g[r];
      u_[r] = de*u_[r] + m_[r];
      ob[(size_t)r*DHX] = u_[r];
    }
    fa0=na0; fb0=nb0; fa1=na1; fb1=nb1;
  }
}

extern "C" void kernel_launch(void* const* d_in, const int* in_sizes, int n_in,
                              void* d_out, int out_size, void* d_ws, size_t ws_size,
                              hipStream_t stream) {
  (void)in_sizes; (void)n_in; (void)out_size; (void)ws_size;
  const float* seq   = (const float*)d_in[0];
  const float* scale = (const float*)d_in[1];
  const float* Wkv   = (const float*)d_in[2];
  const float* Wstep = (const float*)d_in[3];
  const float* Wmom  = (const float*)d_in[4];
  const float* Wdec  = (const float*)d_in[5];
  const float* w0    = (const float*)d_in[6];
  const float* w1    = (const float*)d_in[7];
  float* out = (float*)d_out;
  float* ws  = (float*)d_ws;

  // workspace layout (float units)
  ushort_t* fac0 = (ushort_t*)(ws);              // 4,194,304 ushorts
  ushort_t* fac1 = (ushort_t*)(ws + 2097152);    // 4,194,304 ushorts
  ushort_t* WkvT = (ushort_t*)(ws + 4194304);    // 524,288 ushorts
  ushort_t* w0T  = (ushort_t*)(ws + 4456448);    // 131,072 ushorts
  ushort_t* w1T  = (ushort_t*)(ws + 4521984);    // 131,072 ushorts
  ushort_t* w1n  = (ushort_t*)(ws + 4587520);    // 131,072 ushorts
  float*    momw = ws + 4653056;                 // 1,024
  float*    decw = ws + 4654080;                 // 1,024
  float*    wfsS = ws + 4655104;                 // 2,048
  float*    wfsM = ws + 4657152;                 // 2,048
  float*    wfsD = ws + 4659200;                 // 2,048

  k_prep<<<dim3(73), dim3(256), 0, stream>>>(Wkv, w0, w1, scale, Wstep, Wmom, Wdec,
      WkvT, w0T, w1T, w1n, wfsS, wfsM, wfsD);
  k_fused5<<<dim3(256), dim3(1024), 0, stream>>>(seq, scale, wfsS, wfsM, wfsD,
      WkvT, w0T, w1T, w1n, fac0, fac1, momw, decw);
  k_scan3<<<dim3(1024), dim3(64), 0, stream>>>(fac0, fac1, momw, decw, out);
}